// Round 4
// baseline (203.580 us; speedup 1.0000x reference)
//
#include <hip/hip_runtime.h>
#include <math.h>

// Problem constants
#define BQ 64
#define NOBJ 5
#define CIN 3
#define IMG_H 64
#define IMG_W 96
#define OH 32
#define OW 48
#define OC 128
#define NPAIR 25
#define PP 4
#define CONV_OUT 32

// Tiling: each block = (src, b, rowgroup of 2 output rows)
#define NRG 16                          // 32 output rows / 2
#define IN_ROWS 5                       // input rows per rowgroup
#define LSTRIDE 98                      // shorts per staged row (needs 97)
#define NCH (NOBJ * CIN)                // 15
#define IMG_ELEMS (NCH * IN_ROWS * LSTRIDE)    // 7350 shorts = 14.7 KB
#define NPOS 96                         // 2 output rows x 48 cols
#define XK 32                           // padded K (27 real + bias + zeros)
#define X_ELEMS (NOBJ * NPOS * XK)      // 15360 shorts = 30.7 KB

#define NPRED (2 * 1600 * PP)           // 12800
#define ADJ_N (BQ * 1600)               // 102400

typedef __attribute__((ext_vector_type(8))) short short8;
typedef __attribute__((ext_vector_type(4))) float float4_;

__device__ inline unsigned short f2bf(float f) {
    unsigned u = __builtin_bit_cast(unsigned, f);
    u += 0x7fff + ((u >> 16) & 1);          // round-to-nearest-even
    return (unsigned short)(u >> 16);
}

// T[src][b][rg][pair][mt] partial sums; mt = 16-oc tile 0..7, p = mt>>1.
// T fully written by conv kernel -> no memset, no atomics.
__global__ __launch_bounds__(256) void conv_pair_mfma(
    const float* __restrict__ state,
    const float* __restrict__ state_next,
    const float* __restrict__ conv_w,
    const float* __restrict__ conv_b,
    const float* __restrict__ w2,
    float* __restrict__ T)
{
    __shared__ __align__(16) unsigned short sImg[IMG_ELEMS];
    __shared__ __align__(16) unsigned short sX[X_ELEMS];

    const int tid = threadIdx.x;
    const int rg  = blockIdx.x;     // 0..15
    const int b   = blockIdx.y;     // 0..63
    const int src = blockIdx.z;     // 0..1

    const float* g = (src == 0 ? state : state_next)
                   + (size_t)b * NCH * IMG_H * IMG_W;
    const int R0 = rg * 4;          // first input row of this rowgroup

    // ---- stage 1: image rows -> bf16 LDS (coalesced global reads) ----
    for (int idx = tid; idx < IMG_ELEMS; idx += 256) {
        int col  = idx % LSTRIDE;
        int rest = idx / LSTRIDE;
        int lr   = rest % IN_ROWS;
        int ch   = rest / IN_ROWS;          // obj*3+ci
        int gr   = R0 + lr;
        float v = 0.f;
        if (col < IMG_W && gr < IMG_H)
            v = g[ch * (IMG_H * IMG_W) + gr * IMG_W + col];
        sImg[idx] = f2bf(v);
    }
    __syncthreads();

    // ---- stage 2: build im2col sX[obj][pos][k], k=27 -> 1.0 (bias), k>27 -> 0.
    // unit u = obj*384 + pos*4 + subk; write addr = u*16 B -> wave-contiguous,
    // conflict-free ds_write_b128.
    for (int u = tid; u < NOBJ * NPOS * 4; u += 256) {
        int subk = u & 3;
        int pl   = (u >> 2) % NPOS;
        int obj  = u / (4 * NPOS);
        int rl   = pl / 48;
        int pc   = pl - rl * 48;
        short8 vals;
        #pragma unroll
        for (int j = 0; j < 8; ++j) {
            int k = subk * 8 + j;
            unsigned short hv = 0;
            if (k < 27) {
                int ci = k / 9;
                int r9 = k - ci * 9;
                int kh = r9 / 3;
                int kw = r9 - kh * 3;
                hv = sImg[((obj * CIN + ci) * IN_ROWS + 2 * rl + kh) * LSTRIDE + 2 * pc + kw];
            } else if (k == 27) {
                hv = 0x3f80;                // 1.0 bf16 (pairs with bias in A)
            }
            vals[j] = (short)hv;
        }
        *(short8*)&sX[(size_t)u * 8] = vals;
    }

    const int wave = tid >> 6;
    const int lane = tid & 63;
    const int quad = lane >> 4;
    const int ocl  = lane & 15;

    __syncthreads();

    const float4_ zero4 = {0.f, 0.f, 0.f, 0.f};

    #pragma unroll
    for (int pass = 0; pass < 2; ++pass) {
        const int mt  = wave + pass * 4;    // oc-tile 0..7
        const int p   = mt >> 1;            // predicate group
        const int row = mt * 16 + ocl;      // this lane's weight row (oc)

        // weights straight from global (27 KB, L2-resident), bias at k=27
        short8 wa, wb;
        #pragma unroll
        for (int j = 0; j < 8; ++j) {
            int k = quad * 8 + j;
            float va = 0.f, vb = 0.f;
            if (k < 27) {
                va = conv_w[row * 54 + k];
                vb = conv_w[row * 54 + 27 + k];
            } else if (k == 27) {
                va = conv_b[row];
            }
            wa[j] = (short)f2bf(va);
            wb[j] = (short)f2bf(vb);
        }
        float w2v[4];
        #pragma unroll
        for (int r = 0; r < 4; ++r)
            w2v[r] = w2[p * CONV_OUT + (mt & 1) * 16 + quad * 4 + r];

        float acc[NPAIR];
        #pragma unroll
        for (int q = 0; q < NPAIR; ++q) acc[q] = 0.f;

        for (int nt = 0; nt < 6; ++nt) {    // 2 rows x 3 col-tiles of 16
            const int rl  = nt / 3;
            const int c0  = (nt - rl * 3) * 16;
            const int pos = rl * 48 + c0 + ocl;

            // one ds_read_b128 per (obj): wave covers contiguous 1KB -> conflict-free
            short8 xf[NOBJ];
            #pragma unroll
            for (int obj = 0; obj < NOBJ; ++obj)
                xf[obj] = *(const short8*)&sX[((size_t)(obj * NPOS + pos)) * XK + quad * 8];

            float4_ av[NOBJ];
            #pragma unroll
            for (int obj = 0; obj < NOBJ; ++obj)
                av[obj] = __builtin_amdgcn_mfma_f32_16x16x32_bf16(wa, xf[obj], zero4, 0, 0, 0);

            #pragma unroll
            for (int jo = 0; jo < NOBJ; ++jo) {
                float4_ bv = __builtin_amdgcn_mfma_f32_16x16x32_bf16(wb, xf[jo], zero4, 0, 0, 0);
                #pragma unroll
                for (int i = 0; i < NOBJ; ++i) {
                    float s = 0.f;
                    #pragma unroll
                    for (int r = 0; r < 4; ++r) {
                        float v = av[i][r] + bv[r];
                        v = fmaxf(v, 0.f);
                        s = fmaf(w2v[r], v, s);
                    }
                    acc[i * NOBJ + jo] += s;
                }
            }
        }

        // ---- wave-reduce each pair across 64 lanes; direct store (no atomics) ----
        float myv = 0.f;
        #pragma unroll
        for (int q = 0; q < NPAIR; ++q) {
            float rr = acc[q];
            #pragma unroll
            for (int off = 32; off > 0; off >>= 1)
                rr += __shfl_xor(rr, off, 64);
            if (lane == q) myv = rr;
        }
        if (lane < NPAIR)
            T[((((size_t)src * BQ + b) * NRG + rg) * NPAIR + lane) * 8 + mt] = myv;
    }
}

__global__ __launch_bounds__(256) void epilogue_kernel(
    const float* __restrict__ T,
    const float* __restrict__ b2,
    const float* __restrict__ temp,
    float* __restrict__ out)
{
    int idx = blockIdx.x * blockDim.x + threadIdx.x;
    if (idx < NPRED) {
        int p   = idx & 3;
        int t   = (idx >> 2) % 1600;
        int src = idx / 6400;
        int bb  = t / NPAIR;
        int pr  = t - bb * NPAIR;
        const float* base = T + ((((size_t)src * BQ + bb) * NRG) * NPAIR + pr) * 8 + 2 * p;
        float sum = 0.f;
        #pragma unroll
        for (int rg = 0; rg < NRG; ++rg) {
            sum += base[(size_t)rg * NPAIR * 8];
            sum += base[(size_t)rg * NPAIR * 8 + 1];
        }
        float logit = sum * (1.0f / (OH * OW)) + b2[p];
        float x = logit / temp[0];
        out[idx] = 1.0f / (1.0f + expf(-x));
    } else if (idx < NPRED + ADJ_N) {
        int a = idx - NPRED;
        int bb = a / 1600;
        int t  = a - bb * 1600;
        out[idx] = (t / NPAIR == bb) ? 1.0f : 0.0f;
    }
}

extern "C" void kernel_launch(void* const* d_in, const int* in_sizes, int n_in,
                              void* d_out, int out_size, void* d_ws, size_t ws_size,
                              hipStream_t stream)
{
    const float* state      = (const float*)d_in[0];
    const float* state_next = (const float*)d_in[1];
    const float* conv_w     = (const float*)d_in[2];
    const float* conv_b     = (const float*)d_in[3];
    const float* w2         = (const float*)d_in[4];
    const float* b2         = (const float*)d_in[5];
    // d_in[6] = n_obj (always 5)
    const float* temp       = (const float*)d_in[7];

    float* out = (float*)d_out;
    float* T   = (float*)d_ws;              // [2][64][16][25][8] floats = 1.64 MB

    dim3 grid1(NRG, BQ, 2);                 // 2048 blocks
    conv_pair_mfma<<<grid1, 256, 0, stream>>>(state, state_next, conv_w, conv_b, w2, T);

    epilogue_kernel<<<(NPRED + ADJ_N + 255) / 256, 256, 0, stream>>>(T, b2, temp, out);
}

// Round 5
// 192.311 us; speedup vs baseline: 1.0586x; 1.0586x over previous
//
#include <hip/hip_runtime.h>
#include <math.h>

// Problem constants
#define BQ 64
#define NOBJ 5
#define CIN 3
#define IMG_H 64
#define IMG_W 96
#define OH 32
#define OW 48
#define OC 128
#define NPAIR 25
#define PP 4
#define CONV_OUT 32

// Tiling: each block = (src, b, rowgroup of 2 output rows)
#define NRG 16                          // 32 output rows / 2
#define NPOS 96                         // 2 output rows x 48 cols
#define XK 32                           // padded K (27 real + bias + zeros)
#define X_ELEMS (NOBJ * NPOS * XK)      // 15360 shorts = 30.7 KB

#define NPRED (2 * 1600 * PP)           // 12800
#define ADJ_N (BQ * 1600)               // 102400

typedef __attribute__((ext_vector_type(8))) short short8;
typedef __attribute__((ext_vector_type(4))) float float4_;
typedef __attribute__((ext_vector_type(2))) float pf2;

__device__ inline unsigned short f2bf(float f) {
    unsigned u = __builtin_bit_cast(unsigned, f);
    u += 0x7fff + ((u >> 16) & 1);          // round-to-nearest-even
    return (unsigned short)(u >> 16);
}

// T[src][b][rg][pair][mt] partial sums; mt = 16-oc tile 0..7, p = mt>>1.
// T fully written by conv kernel -> no memset, no atomics.
__global__ __launch_bounds__(256) void conv_pair_mfma(
    const float* __restrict__ state,
    const float* __restrict__ state_next,
    const float* __restrict__ conv_w,
    const float* __restrict__ conv_b,
    const float* __restrict__ w2,
    float* __restrict__ T)
{
    __shared__ __align__(16) unsigned short sX[X_ELEMS];   // 30.7 KB only

    const int tid = threadIdx.x;
    const int rg  = blockIdx.x;     // 0..15
    const int b   = blockIdx.y;     // 0..63
    const int src = blockIdx.z;     // 0..1

    const float* g = (src == 0 ? state : state_next)
                   + (size_t)b * NOBJ * CIN * IMG_H * IMG_W;
    const int R0 = rg * 4;          // first input row of this rowgroup

    // ---- build im2col sX[obj][pos][k] DIRECTLY from global (no sImg stage).
    // unit u = obj*384 + pos*4 + subk; subk = tid&3 is constant per thread.
    // k = subk*8 + j; k==27 -> 1.0 (bias partner), k>27 -> 0, OOB -> 0.
    {
        const int subk = tid & 3;
        int koff[8], khv[8], kwv[8];
        unsigned short padv[8];
        bool kval[8];
        #pragma unroll
        for (int j = 0; j < 8; ++j) {
            int k = subk * 8 + j;
            if (k < 27) {
                int ci = k / 9;
                int r9 = k - ci * 9;
                int kh = r9 / 3;
                int kw = r9 - kh * 3;
                koff[j] = ci * (IMG_H * IMG_W) + kh * IMG_W + kw;
                khv[j] = kh; kwv[j] = kw; kval[j] = true; padv[j] = 0;
            } else {
                koff[j] = 0; khv[j] = 0; kwv[j] = 0; kval[j] = false;
                padv[j] = (k == 27) ? (unsigned short)0x3f80 : (unsigned short)0;
            }
        }
        for (int u = tid; u < NOBJ * NPOS * 4; u += 256) {
            int pl  = (u >> 2) % NPOS;          // 0..95
            int obj = u / (NPOS * 4);
            int rl  = (pl >= 48) ? 1 : 0;
            int pc  = pl - rl * 48;
            int gr0 = R0 + 2 * rl;
            int gc0 = 2 * pc;
            const float* gp = g + obj * (CIN * IMG_H * IMG_W) + gr0 * IMG_W + gc0;
            short8 vals;
            #pragma unroll
            for (int j = 0; j < 8; ++j) {
                unsigned short hv = padv[j];
                if (kval[j] && (gr0 + khv[j] < IMG_H) && (gc0 + kwv[j] < IMG_W))
                    hv = f2bf(gp[koff[j]]);
                vals[j] = (short)hv;
            }
            *(short8*)&sX[(size_t)u * 8] = vals;    // contiguous b128 writes
        }
    }

    const int wave = tid >> 6;
    const int lane = tid & 63;
    const int quad = lane >> 4;
    const int ocl  = lane & 15;

    __syncthreads();

    const float4_ zero4 = {0.f, 0.f, 0.f, 0.f};

    #pragma unroll
    for (int pass = 0; pass < 2; ++pass) {
        const int mt  = wave + pass * 4;    // oc-tile 0..7
        const int p   = mt >> 1;            // predicate group
        const int row = mt * 16 + ocl;      // this lane's weight row (oc)

        // weights straight from global (27 KB, L2-resident), bias at k=27
        short8 wa, wb;
        #pragma unroll
        for (int j = 0; j < 8; ++j) {
            int k = quad * 8 + j;
            float va = 0.f, vb = 0.f;
            if (k < 27) {
                va = conv_w[row * 54 + k];
                vb = conv_w[row * 54 + 27 + k];
            } else if (k == 27) {
                va = conv_b[row];
            }
            wa[j] = (short)f2bf(va);
            wb[j] = (short)f2bf(vb);
        }
        pf2 w2lo, w2hi;
        w2lo[0] = w2[p * CONV_OUT + (mt & 1) * 16 + quad * 4 + 0];
        w2lo[1] = w2[p * CONV_OUT + (mt & 1) * 16 + quad * 4 + 1];
        w2hi[0] = w2[p * CONV_OUT + (mt & 1) * 16 + quad * 4 + 2];
        w2hi[1] = w2[p * CONV_OUT + (mt & 1) * 16 + quad * 4 + 3];

        float acc[NPAIR];
        #pragma unroll
        for (int q = 0; q < NPAIR; ++q) acc[q] = 0.f;

        for (int nt = 0; nt < 6; ++nt) {    // 2 rows x 3 col-tiles of 16
            const int rl  = nt / 3;
            const int c0  = (nt - rl * 3) * 16;
            const int pos = rl * 48 + c0 + ocl;

            // one ds_read_b128 per obj: wave covers contiguous 1KB -> conflict-free
            short8 xf[NOBJ];
            #pragma unroll
            for (int obj = 0; obj < NOBJ; ++obj)
                xf[obj] = *(const short8*)&sX[((size_t)(obj * NPOS + pos)) * XK + quad * 8];

            pf2 alo[NOBJ], ahi[NOBJ];
            #pragma unroll
            for (int obj = 0; obj < NOBJ; ++obj) {
                float4_ a = __builtin_amdgcn_mfma_f32_16x16x32_bf16(wa, xf[obj], zero4, 0, 0, 0);
                alo[obj][0] = a[0]; alo[obj][1] = a[1];
                ahi[obj][0] = a[2]; ahi[obj][1] = a[3];
            }

            #pragma unroll
            for (int jo = 0; jo < NOBJ; ++jo) {
                float4_ bq = __builtin_amdgcn_mfma_f32_16x16x32_bf16(wb, xf[jo], zero4, 0, 0, 0);
                pf2 blo, bhi;
                blo[0] = bq[0]; blo[1] = bq[1];
                bhi[0] = bq[2]; bhi[1] = bq[3];
                #pragma unroll
                for (int i = 0; i < NOBJ; ++i) {
                    pf2 v0 = alo[i] + blo;          // v_pk_add_f32
                    pf2 v1 = ahi[i] + bhi;
                    v0[0] = fmaxf(v0[0], 0.f); v0[1] = fmaxf(v0[1], 0.f);
                    v1[0] = fmaxf(v1[0], 0.f); v1[1] = fmaxf(v1[1], 0.f);
                    pf2 s2 = v0 * w2lo + v1 * w2hi; // pk_mul + pk_fma
                    acc[i * NOBJ + jo] += s2[0] + s2[1];
                }
            }
        }

        // ---- wave-reduce each pair across 64 lanes; direct store (no atomics) ----
        float myv = 0.f;
        #pragma unroll
        for (int q = 0; q < NPAIR; ++q) {
            float rr = acc[q];
            #pragma unroll
            for (int off = 32; off > 0; off >>= 1)
                rr += __shfl_xor(rr, off, 64);
            if (lane == q) myv = rr;
        }
        if (lane < NPAIR)
            T[((((size_t)src * BQ + b) * NRG + rg) * NPAIR + lane) * 8 + mt] = myv;
    }
}

// blocks 0..127: predicates via LDS-cooperative T reduction (one block per src,b)
// blocks 128..527: adjacency mask
__global__ __launch_bounds__(256) void epilogue_kernel(
    const float* __restrict__ T,
    const float* __restrict__ b2,
    const float* __restrict__ temp,
    float* __restrict__ out)
{
    const int blk = blockIdx.x;
    if (blk < 2 * BQ) {
        __shared__ float sT[NRG * NPAIR * 8];   // 12.8 KB
        const int src = blk >> 6;
        const int b   = blk & 63;
        const float* tp = T + ((size_t)(src * BQ + b)) * NRG * NPAIR * 8;
        for (int i = threadIdx.x; i < NRG * NPAIR * 8; i += 256)
            sT[i] = tp[i];                       // fully coalesced
        __syncthreads();
        const int t = threadIdx.x;
        if (t < NPAIR * PP) {
            const int pair = t >> 2;
            const int p    = t & 3;
            float sum = 0.f;
            #pragma unroll
            for (int rgi = 0; rgi < NRG; ++rgi) {
                const float* sp = &sT[(rgi * NPAIR + pair) * 8 + 2 * p];
                sum += sp[0] + sp[1];
            }
            float logit = sum * (1.0f / (OH * OW)) + b2[p];
            float x = logit / temp[0];
            out[(size_t)src * 6400 + (b * NPAIR + pair) * 4 + p] =
                1.0f / (1.0f + expf(-x));
        }
    } else {
        int a = (blk - 2 * BQ) * 256 + threadIdx.x;
        if (a < ADJ_N) {
            int bb = a / 1600;
            int t  = a - bb * 1600;
            out[NPRED + a] = (t / NPAIR == bb) ? 1.0f : 0.0f;
        }
    }
}

extern "C" void kernel_launch(void* const* d_in, const int* in_sizes, int n_in,
                              void* d_out, int out_size, void* d_ws, size_t ws_size,
                              hipStream_t stream)
{
    const float* state      = (const float*)d_in[0];
    const float* state_next = (const float*)d_in[1];
    const float* conv_w     = (const float*)d_in[2];
    const float* conv_b     = (const float*)d_in[3];
    const float* w2         = (const float*)d_in[4];
    const float* b2         = (const float*)d_in[5];
    // d_in[6] = n_obj (always 5)
    const float* temp       = (const float*)d_in[7];

    float* out = (float*)d_out;
    float* T   = (float*)d_ws;              // [2][64][16][25][8] floats = 1.64 MB

    dim3 grid1(NRG, BQ, 2);                 // 2048 blocks
    conv_pair_mfma<<<grid1, 256, 0, stream>>>(state, state_next, conv_w, conv_b, w2, T);

    const int adj_blocks = (ADJ_N + 255) / 256;          // 400
    epilogue_kernel<<<2 * BQ + adj_blocks, 256, 0, stream>>>(T, b2, temp, out);
}

// Round 6
// 189.001 us; speedup vs baseline: 1.0771x; 1.0175x over previous
//
#include <hip/hip_runtime.h>
#include <math.h>

// Problem constants
#define BQ 64
#define NOBJ 5
#define CIN 3
#define IMG_H 64
#define IMG_W 96
#define OH 32
#define OW 48
#define OC 128
#define NPAIR 25
#define PP 4
#define CONV_OUT 32

// Tiling: each block = (src, b, rowgroup of 2 output rows); 512 threads = 8 waves
#define NRG 16                          // 32 output rows / 2
#define NPOS 96                         // 2 output rows x 48 cols
#define XK 32                           // padded K (27 real + bias + zeros)
#define X_ELEMS (NOBJ * NPOS * XK)      // 15360 shorts = 30.7 KB

#define NPRED (2 * 1600 * PP)           // 12800
#define ADJ_N (BQ * 1600)               // 102400

typedef __attribute__((ext_vector_type(8))) short short8;
typedef __attribute__((ext_vector_type(4))) float float4_;
typedef __attribute__((ext_vector_type(2))) float pf2;

__device__ inline unsigned short f2bf(float f) {
    unsigned u = __builtin_bit_cast(unsigned, f);
    u += 0x7fff + ((u >> 16) & 1);          // round-to-nearest-even
    return (unsigned short)(u >> 16);
}

// T[src][b][rg][pair][mt]; mt = 16-oc tile 0..7 (p = mt>>1). Fully written,
// no memset, no atomics. Conv blocks with src==1 also write the adj mask.
__global__ __launch_bounds__(512) void conv_pair_mfma(
    const float* __restrict__ state,
    const float* __restrict__ state_next,
    const float* __restrict__ conv_w,
    const float* __restrict__ conv_b,
    const float* __restrict__ w2,
    float* __restrict__ T,
    float* __restrict__ out)
{
    __shared__ __align__(16) unsigned short sX[X_ELEMS];   // 30.7 KB

    const int tid = threadIdx.x;
    const int rg  = blockIdx.x;     // 0..15
    const int b   = blockIdx.y;     // 0..63
    const int src = blockIdx.z;     // 0..1

    const float* g = (src == 0 ? state : state_next)
                   + (size_t)b * NOBJ * CIN * IMG_H * IMG_W;
    const int R0 = rg * 4;          // first input row of this rowgroup

    // ---- adj mask from src==1 blocks (independent of everything; pre-barrier)
    if (src == 1 && tid < 100) {
        int a  = (rg + NRG * b) * 100 + tid;     // 1024 blocks x 100 = 102400
        int bb = a / 1600;
        int t  = a - bb * 1600;
        out[NPRED + a] = (t / NPAIR == bb) ? 1.0f : 0.0f;
    }

    // ---- build im2col sX[obj][pos][k] directly from global.
    // unit u = obj*384 + pos*4 + subk; subk = tid&3 (u += 512 preserves u&3).
    // k = subk*8 + j; k==27 -> 1.0 (bias partner), k>27 -> 0, OOB -> 0.
    {
        const int subk = tid & 3;
        int koff[8], khv[8], kwv[8];
        unsigned short padv[8];
        bool kval[8];
        #pragma unroll
        for (int j = 0; j < 8; ++j) {
            int k = subk * 8 + j;
            if (k < 27) {
                int ci = k / 9;
                int r9 = k - ci * 9;
                int kh = r9 / 3;
                int kw = r9 - kh * 3;
                koff[j] = ci * (IMG_H * IMG_W) + kh * IMG_W + kw;
                khv[j] = kh; kwv[j] = kw; kval[j] = true; padv[j] = 0;
            } else {
                koff[j] = 0; khv[j] = 0; kwv[j] = 0; kval[j] = false;
                padv[j] = (k == 27) ? (unsigned short)0x3f80 : (unsigned short)0;
            }
        }
        for (int u = tid; u < NOBJ * NPOS * 4; u += 512) {
            int pl  = (u >> 2) % NPOS;          // 0..95
            int obj = u / (NPOS * 4);
            int rl  = (pl >= 48) ? 1 : 0;
            int pc  = pl - rl * 48;
            int gr0 = R0 + 2 * rl;
            int gc0 = 2 * pc;
            const float* gp = g + obj * (CIN * IMG_H * IMG_W) + gr0 * IMG_W + gc0;
            short8 vals;
            #pragma unroll
            for (int j = 0; j < 8; ++j) {
                unsigned short hv = padv[j];
                if (kval[j] && (gr0 + khv[j] < IMG_H) && (gc0 + kwv[j] < IMG_W))
                    hv = f2bf(gp[koff[j]]);
                vals[j] = (short)hv;
            }
            *(short8*)&sX[(size_t)u * 8] = vals;    // contiguous b128 writes
        }
    }

    const int wave = tid >> 6;      // 0..7 -> mt
    const int lane = tid & 63;
    const int quad = lane >> 4;
    const int ocl  = lane & 15;

    const int mt  = wave;
    const int p   = mt >> 1;
    const int row = mt * 16 + ocl;  // this lane's weight row (oc)

    // weights straight from global (27 KB, L2-resident), bias at k=27
    short8 wa, wb;
    #pragma unroll
    for (int j = 0; j < 8; ++j) {
        int k = quad * 8 + j;
        float va = 0.f, vb = 0.f;
        if (k < 27) {
            va = conv_w[row * 54 + k];
            vb = conv_w[row * 54 + 27 + k];
        } else if (k == 27) {
            va = conv_b[row];
        }
        wa[j] = (short)f2bf(va);
        wb[j] = (short)f2bf(vb);
    }
    pf2 w2lo, w2hi;
    w2lo[0] = w2[p * CONV_OUT + (mt & 1) * 16 + quad * 4 + 0];
    w2lo[1] = w2[p * CONV_OUT + (mt & 1) * 16 + quad * 4 + 1];
    w2hi[0] = w2[p * CONV_OUT + (mt & 1) * 16 + quad * 4 + 2];
    w2hi[1] = w2[p * CONV_OUT + (mt & 1) * 16 + quad * 4 + 3];

    __syncthreads();

    const float4_ zero4 = {0.f, 0.f, 0.f, 0.f};

    float acc[NPAIR];
    #pragma unroll
    for (int q = 0; q < NPAIR; ++q) acc[q] = 0.f;

    for (int nt = 0; nt < 6; ++nt) {    // 2 rows x 3 col-tiles of 16
        const int rl  = nt / 3;
        const int c0  = (nt - rl * 3) * 16;
        const int pos = rl * 48 + c0 + ocl;

        pf2 alo[NOBJ], ahi[NOBJ];
        short8 xf[NOBJ];
        #pragma unroll
        for (int obj = 0; obj < NOBJ; ++obj) {
            xf[obj] = *(const short8*)&sX[((size_t)(obj * NPOS + pos)) * XK + quad * 8];
            float4_ a = __builtin_amdgcn_mfma_f32_16x16x32_bf16(wa, xf[obj], zero4, 0, 0, 0);
            alo[obj][0] = a[0]; alo[obj][1] = a[1];
            ahi[obj][0] = a[2]; ahi[obj][1] = a[3];
        }

        #pragma unroll
        for (int jo = 0; jo < NOBJ; ++jo) {
            float4_ bq = __builtin_amdgcn_mfma_f32_16x16x32_bf16(wb, xf[jo], zero4, 0, 0, 0);
            pf2 blo, bhi;
            blo[0] = bq[0]; blo[1] = bq[1];
            bhi[0] = bq[2]; bhi[1] = bq[3];
            #pragma unroll
            for (int i = 0; i < NOBJ; ++i) {
                pf2 v0 = alo[i] + blo;          // v_pk_add_f32
                pf2 v1 = ahi[i] + bhi;
                v0[0] = fmaxf(v0[0], 0.f); v0[1] = fmaxf(v0[1], 0.f);
                v1[0] = fmaxf(v1[0], 0.f); v1[1] = fmaxf(v1[1], 0.f);
                pf2 s2 = v0 * w2lo + v1 * w2hi; // pk_mul + pk_fma
                acc[i * NOBJ + jo] += s2[0] + s2[1];
            }
        }
    }

    // ---- wave-reduce each pair across 64 lanes; direct store (no atomics) ----
    float myv = 0.f;
    #pragma unroll
    for (int q = 0; q < NPAIR; ++q) {
        float rr = acc[q];
        #pragma unroll
        for (int off = 32; off > 0; off >>= 1)
            rr += __shfl_xor(rr, off, 64);
        if (lane == q) myv = rr;
    }
    if (lane < NPAIR)
        T[((((size_t)src * BQ + b) * NRG + rg) * NPAIR + lane) * 8 + mt] = myv;
}

// predicates only: 12800 threads
__global__ __launch_bounds__(256) void pred_kernel(
    const float* __restrict__ T,
    const float* __restrict__ b2,
    const float* __restrict__ temp,
    float* __restrict__ out)
{
    int idx = blockIdx.x * blockDim.x + threadIdx.x;
    if (idx >= NPRED) return;
    int p   = idx & 3;
    int t   = (idx >> 2) % 1600;
    int src = idx / 6400;
    int bb  = t / NPAIR;
    int pr  = t - bb * NPAIR;
    const float* base = T + ((((size_t)src * BQ + bb) * NRG) * NPAIR + pr) * 8 + 2 * p;
    float sum = 0.f;
    #pragma unroll
    for (int rgi = 0; rgi < NRG; ++rgi) {
        sum += base[(size_t)rgi * NPAIR * 8];
        sum += base[(size_t)rgi * NPAIR * 8 + 1];
    }
    float logit = sum * (1.0f / (OH * OW)) + b2[p];
    float x = logit / temp[0];
    out[idx] = 1.0f / (1.0f + expf(-x));
}

extern "C" void kernel_launch(void* const* d_in, const int* in_sizes, int n_in,
                              void* d_out, int out_size, void* d_ws, size_t ws_size,
                              hipStream_t stream)
{
    const float* state      = (const float*)d_in[0];
    const float* state_next = (const float*)d_in[1];
    const float* conv_w     = (const float*)d_in[2];
    const float* conv_b     = (const float*)d_in[3];
    const float* w2         = (const float*)d_in[4];
    const float* b2         = (const float*)d_in[5];
    // d_in[6] = n_obj (always 5)
    const float* temp       = (const float*)d_in[7];

    float* out = (float*)d_out;
    float* T   = (float*)d_ws;              // [2][64][16][25][8] floats = 1.64 MB

    dim3 grid1(NRG, BQ, 2);                 // 2048 blocks x 512 threads
    conv_pair_mfma<<<grid1, 512, 0, stream>>>(state, state_next, conv_w, conv_b,
                                              w2, T, out);

    pred_kernel<<<(NPRED + 255) / 256, 256, 0, stream>>>(T, b2, temp, out);
}